// Round 2
// baseline (123.813 us; speedup 1.0000x reference)
//
#include <hip/hip_runtime.h>

// DCN cross layer, B=16384, D=1024, L=3, fp32.
//   cross = x
//   for i in L: s = dot(cross, W[i]); cross = x*s + bias[i] + cross
//
// Memory-bound: 64 MiB read (x) + 64 MiB write (out); W/bias 12 KiB each
// (L1-resident). One 64-lane wave handles TWO rows (independent dependency
// chains -> ILP hides the shuffle-reduction latency). cross lives entirely
// in registers; no LDS, no barriers.

#define D_DIM 1024
#define N_LAYER 3
#define WAVES_PER_BLOCK 4
#define ROWS_PER_WAVE 2
#define ROWS_PER_BLOCK (WAVES_PER_BLOCK * ROWS_PER_WAVE)  // 8

__global__ __launch_bounds__(256, 4) void cross_layer_kernel(
    const float* __restrict__ x,
    const float* __restrict__ W,
    const float* __restrict__ bias,
    float* __restrict__ out,
    int n_rows)
{
    const int wave = threadIdx.x >> 6;   // 0..3
    const int lane = threadIdx.x & 63;   // 0..63
    const int row0 = blockIdx.x * ROWS_PER_BLOCK + wave * ROWS_PER_WAVE;
    const int row1 = row0 + 1;
    if (row0 >= n_rows) return;
    const bool has1 = (row1 < n_rows);

    // Row layout: 1024 floats = 64 lanes * 4 float4 segments, segment j is a
    // contiguous 1 KiB block (coalesced 16 B/lane).
    const float4* xr0 = reinterpret_cast<const float4*>(x + (size_t)row0 * D_DIM);
    const float4* xr1 = reinterpret_cast<const float4*>(x + (size_t)(has1 ? row1 : row0) * D_DIM);

    float4 xv0[4], xv1[4];   // x rows, reused every layer
    float4 cv0[4], cv1[4];   // running cross
    #pragma unroll
    for (int j = 0; j < 4; ++j) {
        xv0[j] = xr0[j * 64 + lane];
        xv1[j] = xr1[j * 64 + lane];
        cv0[j] = xv0[j];
        cv1[j] = xv1[j];
    }

    #pragma unroll
    for (int i = 0; i < N_LAYER; ++i) {
        const float4* wr = reinterpret_cast<const float4*>(W    + i * D_DIM);
        const float4* br = reinterpret_cast<const float4*>(bias + i * D_DIM);

        // per-lane partial dots over each row's 16 elements (two independent chains)
        float p0 = 0.0f, p1 = 0.0f;
        #pragma unroll
        for (int j = 0; j < 4; ++j) {
            const float4 w = wr[j * 64 + lane];
            p0 = fmaf(cv0[j].x, w.x, p0);  p1 = fmaf(cv1[j].x, w.x, p1);
            p0 = fmaf(cv0[j].y, w.y, p0);  p1 = fmaf(cv1[j].y, w.y, p1);
            p0 = fmaf(cv0[j].z, w.z, p0);  p1 = fmaf(cv1[j].z, w.z, p1);
            p0 = fmaf(cv0[j].w, w.w, p0);  p1 = fmaf(cv1[j].w, w.w, p1);
        }

        // 64-lane butterfly reductions, interleaved for ILP
        #pragma unroll
        for (int off = 32; off > 0; off >>= 1) {
            p0 += __shfl_xor(p0, off, 64);
            p1 += __shfl_xor(p1, off, 64);
        }

        // cross = x * s + bias + cross   (all in registers)
        #pragma unroll
        for (int j = 0; j < 4; ++j) {
            const float4 bv = br[j * 64 + lane];
            cv0[j].x = fmaf(xv0[j].x, p0, bv.x + cv0[j].x);
            cv0[j].y = fmaf(xv0[j].y, p0, bv.y + cv0[j].y);
            cv0[j].z = fmaf(xv0[j].z, p0, bv.z + cv0[j].z);
            cv0[j].w = fmaf(xv0[j].w, p0, bv.w + cv0[j].w);
            cv1[j].x = fmaf(xv1[j].x, p1, bv.x + cv1[j].x);
            cv1[j].y = fmaf(xv1[j].y, p1, bv.y + cv1[j].y);
            cv1[j].z = fmaf(xv1[j].z, p1, bv.z + cv1[j].z);
            cv1[j].w = fmaf(xv1[j].w, p1, bv.w + cv1[j].w);
        }
    }

    float4* orow0 = reinterpret_cast<float4*>(out + (size_t)row0 * D_DIM);
    #pragma unroll
    for (int j = 0; j < 4; ++j)
        orow0[j * 64 + lane] = cv0[j];
    if (has1) {
        float4* orow1 = reinterpret_cast<float4*>(out + (size_t)row1 * D_DIM);
        #pragma unroll
        for (int j = 0; j < 4; ++j)
            orow1[j * 64 + lane] = cv1[j];
    }
}

extern "C" void kernel_launch(void* const* d_in, const int* in_sizes, int n_in,
                              void* d_out, int out_size, void* d_ws, size_t ws_size,
                              hipStream_t stream)
{
    const float* x    = (const float*)d_in[0];   // (B, D, 1) f32
    const float* W    = (const float*)d_in[1];   // (L, D, 1) f32
    const float* bias = (const float*)d_in[2];   // (L, D, 1) f32
    float* out = (float*)d_out;                  // (B, D, 1) f32

    const int n_rows = in_sizes[0] / D_DIM;      // 16384
    const int blocks = (n_rows + ROWS_PER_BLOCK - 1) / ROWS_PER_BLOCK;  // 2048

    cross_layer_kernel<<<blocks, 256, 0, stream>>>(x, W, bias, out, n_rows);
}